// Round 1
// baseline (1567.098 us; speedup 1.0000x reference)
//
#include <hip/hip_runtime.h>
#include <hip/hip_bf16.h>

#define NC 80
#define NK 51
#define REG_MAX 16
#define MAX_DET 100
#define A_TOT 8400
#define BS 16

// out layout (float32): num[16] | boxes[16*100*4] | scores[16*100] | classes[16*100] | kpts[16*100*17*3]
#define OUT_NUM 0
#define OUT_BOX 16
#define OUT_SCORE (16 + 16*MAX_DET*4)
#define OUT_CLASS (OUT_SCORE + 16*MAX_DET)
#define OUT_KPT (OUT_CLASS + 16*MAX_DET)

static __device__ __forceinline__ unsigned long long ullmax(unsigned long long a, unsigned long long b) {
    return a > b ? a : b;
}

// -------- Kernel 1: class scores (sigmoid-max + argmax) per anchor --------
template <int C>
__global__ __launch_bounds__(256, 4) void scores_kernel(
    const float* __restrict__ x,    // [BS][C][A]
    const float* __restrict__ w,    // [NC][C]
    const float* __restrict__ bias, // [NC]
    float* __restrict__ max_s,      // [BS][A_TOT]
    int* __restrict__ cls_id,       // [BS][A_TOT]
    int A, int a_off)
{
    int b = blockIdx.y;
    int a = blockIdx.x * blockDim.x + threadIdx.x;
    if (a >= A) return;
    const float* f = x + (long)b * C * A + a;

    float acc[NC];
#pragma unroll
    for (int oc = 0; oc < NC; ++oc) acc[oc] = bias[oc];

#pragma unroll 1
    for (int c0 = 0; c0 < C; c0 += 8) {
        float fv[8];
#pragma unroll
        for (int j = 0; j < 8; ++j) fv[j] = f[(long)(c0 + j) * A];
#pragma unroll
        for (int oc = 0; oc < NC; ++oc) {
#pragma unroll
            for (int j = 0; j < 8; ++j)
                acc[oc] = fmaf(w[oc * C + c0 + j], fv[j], acc[oc]);
        }
    }

    float m = acc[0];
    int mi = 0;
#pragma unroll
    for (int oc = 1; oc < NC; ++oc) {
        if (acc[oc] > m) { m = acc[oc]; mi = oc; }
    }
    float s = 1.0f / (1.0f + expf(-m));
    max_s[b * A_TOT + a_off + a] = s;
    cls_id[b * A_TOT + a_off + a] = mi;
}

// -------- Kernel 2: top-100 per batch (jax.lax.top_k semantics) --------
__global__ __launch_bounds__(1024) void topk_kernel(
    const float* __restrict__ max_s, // [BS][A_TOT]
    const int* __restrict__ cls_id,  // [BS][A_TOT]
    float* __restrict__ out,
    int* __restrict__ top_idx)       // [BS][MAX_DET]
{
    int b = blockIdx.x;
    int tid = threadIdx.x;

    unsigned long long key[9];
#pragma unroll
    for (int i = 0; i < 9; ++i) {
        int a = tid + i * 1024;
        if (a < A_TOT) {
            unsigned u = __float_as_uint(max_s[b * A_TOT + a]); // sigmoid >= 0 -> monotone bits
            key[i] = ((unsigned long long)u << 32) | (unsigned)(0x7FFFFFFF - a);
        } else {
            key[i] = 0ull;
        }
    }

    __shared__ unsigned long long warp_max[16];
    __shared__ unsigned long long winner;

    int cnt = 0;
    for (int k = 0; k < MAX_DET; ++k) {
        unsigned long long best = key[0];
#pragma unroll
        for (int i = 1; i < 9; ++i) best = ullmax(best, key[i]);
        for (int off = 32; off > 0; off >>= 1)
            best = ullmax(best, __shfl_down(best, off, 64));
        if ((tid & 63) == 0) warp_max[tid >> 6] = best;
        __syncthreads();
        if (tid < 16) {
            unsigned long long v = warp_max[tid];
            for (int off = 8; off > 0; off >>= 1)
                v = ullmax(v, __shfl_down(v, off, 16));
            if (tid == 0) winner = v;
        }
        __syncthreads();
        unsigned long long wk = winner;
#pragma unroll
        for (int i = 0; i < 9; ++i)
            if (key[i] == wk) key[i] = 0ull;
        if (tid == 0) {
            float sc = __uint_as_float((unsigned)(wk >> 32));
            int a = 0x7FFFFFFF - (int)(wk & 0xFFFFFFFFull);
            out[OUT_SCORE + b * MAX_DET + k] = sc;
            out[OUT_CLASS + b * MAX_DET + k] = (float)cls_id[b * A_TOT + a];
            top_idx[b * MAX_DET + k] = a;
            if (sc > 0.25f) cnt++;
        }
        __syncthreads();
    }
    if (tid == 0) out[OUT_NUM + b] = (float)cnt;
}

// -------- Kernel 3: decode box + kpts for selected anchors only --------
__global__ __launch_bounds__(128) void decode_kernel(
    const float* __restrict__ x0, const float* __restrict__ x1, const float* __restrict__ x2,
    const float* __restrict__ w2_0, const float* __restrict__ b2_0,
    const float* __restrict__ w2_1, const float* __restrict__ b2_1,
    const float* __restrict__ w2_2, const float* __restrict__ b2_2,
    const float* __restrict__ w4_0, const float* __restrict__ b4_0,
    const float* __restrict__ w4_1, const float* __restrict__ b4_1,
    const float* __restrict__ w4_2, const float* __restrict__ b4_2,
    const int* __restrict__ top_idx,
    float* __restrict__ out)
{
    int b = blockIdx.y;
    int k = blockIdx.x;
    int a = top_idx[b * MAX_DET + k];

    const float* x; const float* w2; const float* bb2; const float* w4; const float* bb4;
    int C, A, W, a_local; float stride;
    if (a < 6400)      { x = x0; C = 128; A = 6400; W = 80; stride = 8.0f;  a_local = a;        w2 = w2_0; bb2 = b2_0; w4 = w4_0; bb4 = b4_0; }
    else if (a < 8000) { x = x1; C = 256; A = 1600; W = 40; stride = 16.0f; a_local = a - 6400; w2 = w2_1; bb2 = b2_1; w4 = w4_1; bb4 = b4_1; }
    else               { x = x2; C = 512; A = 400;  W = 20; stride = 32.0f; a_local = a - 8000; w2 = w2_2; bb2 = b2_2; w4 = w4_2; bb4 = b4_2; }

    __shared__ float fs[512];
    __shared__ float logits[64];
    __shared__ float kraw[NK];
    __shared__ float dist[4];

    int t = threadIdx.x;
    for (int c = t; c < C; c += 128)
        fs[c] = x[((long)b * C + c) * A + a_local];
    __syncthreads();

    if (t < 64 + NK) {
        const float* wrow; float acc;
        if (t < 64) { wrow = w2 + t * C; acc = bb2[t]; }
        else        { wrow = w4 + (t - 64) * C; acc = bb4[t - 64]; }
        for (int c = 0; c < C; ++c) acc = fmaf(wrow[c], fs[c], acc);
        if (t < 64) logits[t] = acc;
        else        kraw[t - 64] = acc;
    }
    __syncthreads();

    if (t < 4) {
        float mx = logits[t * 16];
#pragma unroll
        for (int r = 1; r < 16; ++r) mx = fmaxf(mx, logits[t * 16 + r]);
        float se = 0.0f, sw = 0.0f;
#pragma unroll
        for (int r = 0; r < 16; ++r) {
            float e = expf(logits[t * 16 + r] - mx);
            se += e; sw += e * (float)r;
        }
        dist[t] = sw / se;
    }
    __syncthreads();

    float ax = (float)(a_local % W) + 0.5f;
    float ay = (float)(a_local / W) + 0.5f;

    if (t == 0) {
        float x1c = ax - dist[0], y1c = ay - dist[1];
        float x2c = ax + dist[2], y2c = ay + dist[3];
        float* ob = out + OUT_BOX + ((long)b * MAX_DET + k) * 4;
        ob[0] = (x1c + x2c) * 0.5f * stride;
        ob[1] = (y1c + y2c) * 0.5f * stride;
        ob[2] = (x2c - x1c) * stride;
        ob[3] = (y2c - y1c) * stride;
    }
    if (t < 17) {
        float vx = kraw[t * 3], vy = kraw[t * 3 + 1], vv = kraw[t * 3 + 2];
        float gx = ax - 0.5f, gy = ay - 0.5f;
        float* ok = out + OUT_KPT + (((long)b * MAX_DET + k) * 17 + t) * 3;
        ok[0] = (vx * 2.0f + gx) * stride;
        ok[1] = (vy * 2.0f + gy) * stride;
        ok[2] = 1.0f / (1.0f + expf(-vv));
    }
}

extern "C" void kernel_launch(void* const* d_in, const int* in_sizes, int n_in,
                              void* d_out, int out_size, void* d_ws, size_t ws_size,
                              hipStream_t stream) {
    const float* x0 = (const float*)d_in[0];
    const float* x1 = (const float*)d_in[1];
    const float* x2 = (const float*)d_in[2];
    // cv2 (box): idx 3..8, cv3 (cls): 9..14, cv4 (kpt): 15..20
    const float* w2[3] = {(const float*)d_in[3], (const float*)d_in[5], (const float*)d_in[7]};
    const float* b2[3] = {(const float*)d_in[4], (const float*)d_in[6], (const float*)d_in[8]};
    const float* w3[3] = {(const float*)d_in[9], (const float*)d_in[11], (const float*)d_in[13]};
    const float* b3[3] = {(const float*)d_in[10], (const float*)d_in[12], (const float*)d_in[14]};
    const float* w4[3] = {(const float*)d_in[15], (const float*)d_in[17], (const float*)d_in[19]};
    const float* b4[3] = {(const float*)d_in[16], (const float*)d_in[18], (const float*)d_in[20]};

    float* out = (float*)d_out;

    float* ws_maxs = (float*)d_ws;                    // [16][8400]
    int* ws_cls = (int*)(ws_maxs + BS * A_TOT);       // [16][8400]
    int* ws_top = (int*)(ws_cls + BS * A_TOT);        // [16][100]

    // scores per level
    {
        dim3 g0((6400 + 255) / 256, BS);
        scores_kernel<128><<<g0, 256, 0, stream>>>(x0, w3[0], b3[0], ws_maxs, ws_cls, 6400, 0);
        dim3 g1((1600 + 255) / 256, BS);
        scores_kernel<256><<<g1, 256, 0, stream>>>(x1, w3[1], b3[1], ws_maxs, ws_cls, 1600, 6400);
        dim3 g2((400 + 255) / 256, BS);
        scores_kernel<512><<<g2, 256, 0, stream>>>(x2, w3[2], b3[2], ws_maxs, ws_cls, 400, 8000);
    }
    // top-k
    topk_kernel<<<dim3(BS), 1024, 0, stream>>>(ws_maxs, ws_cls, out, ws_top);
    // decode selected
    decode_kernel<<<dim3(MAX_DET, BS), 128, 0, stream>>>(
        x0, x1, x2,
        w2[0], b2[0], w2[1], b2[1], w2[2], b2[2],
        w4[0], b4[0], w4[1], b4[1], w4[2], b4[2],
        ws_top, out);
}

// Round 2
// 542.670 us; speedup vs baseline: 2.8878x; 2.8878x over previous
//
#include <hip/hip_runtime.h>
#include <hip/hip_bf16.h>

#define NC 80
#define NK 51
#define REG_MAX 16
#define MAX_DET 100
#define A_TOT 8400
#define BS 16

// out layout (float32): num[16] | boxes[16*100*4] | scores[16*100] | classes[16*100] | kpts[16*100*17*3]
#define OUT_NUM 0
#define OUT_BOX 16
#define OUT_SCORE (16 + 16*MAX_DET*4)
#define OUT_CLASS (OUT_SCORE + 16*MAX_DET)
#define OUT_KPT (OUT_CLASS + 16*MAX_DET)

static __device__ __forceinline__ unsigned long long ullmax(unsigned long long a, unsigned long long b) {
    return a > b ? a : b;
}

// -------- Kernel 1: class scores (sigmoid-max + argmax) per anchor --------
// Block: 256 threads = 64 anchors (lane) x 4 waves (20 output channels each).
// Features tiled through LDS in 128-channel chunks; weights via scalar loads
// (wave-uniform base forced by readfirstlane) -> acc[20] stays in VGPRs.
template <int C>
__global__ __launch_bounds__(256) void scores_kernel(
    const float* __restrict__ x,    // [BS][C][A]
    const float* __restrict__ w,    // [NC][C]
    const float* __restrict__ bias, // [NC]
    float* __restrict__ max_s,      // [BS][A_TOT]
    int* __restrict__ cls_id,       // [BS][A_TOT]
    int A, int a_off)
{
    constexpr int CHUNK = 128;
    __shared__ float fs[CHUNK * 64];      // 32 KB
    __shared__ float rm[4][64];
    __shared__ int   ri[4][64];

    int b = blockIdx.y;
    int a0 = blockIdx.x * 64;
    int t = threadIdx.x;
    int lane = t & 63;
    int wv = __builtin_amdgcn_readfirstlane(t >> 6);   // 0..3, wave-uniform
    int oc0 = wv * 20;
    const float* wbase = w + oc0 * C;

    float acc[20];
#pragma unroll
    for (int j = 0; j < 20; ++j) acc[j] = bias[oc0 + j];

    const float* xb = x + (long)b * C * A;

    for (int c0 = 0; c0 < C; c0 += CHUNK) {
        __syncthreads();
        // stage 128 channels x 64 anchors into LDS (float4, coalesced)
#pragma unroll
        for (int i = 0; i < 8; ++i) {            // 2048 float4 / 256 threads
            int idx = t + i * 256;
            int c = idx >> 4;
            int q = (idx & 15) * 4;
            int aa = a0 + q;
            if (aa > A - 4) aa = A - 4;          // clamp (tail lanes discarded at store)
            float4 v = *(const float4*)(xb + (long)(c0 + c) * A + aa);
            *(float4*)(&fs[c * 64 + q]) = v;
        }
        __syncthreads();

#pragma unroll 1
        for (int c = 0; c < CHUNK; c += 4) {
            float fv0 = fs[(c + 0) * 64 + lane];
            float fv1 = fs[(c + 1) * 64 + lane];
            float fv2 = fs[(c + 2) * 64 + lane];
            float fv3 = fs[(c + 3) * 64 + lane];
#pragma unroll
            for (int j = 0; j < 20; ++j) {
                float w0 = wbase[j * C + c0 + c + 0];
                float w1 = wbase[j * C + c0 + c + 1];
                float w2 = wbase[j * C + c0 + c + 2];
                float w3 = wbase[j * C + c0 + c + 3];
                acc[j] = fmaf(w0, fv0, acc[j]);
                acc[j] = fmaf(w1, fv1, acc[j]);
                acc[j] = fmaf(w2, fv2, acc[j]);
                acc[j] = fmaf(w3, fv3, acc[j]);
            }
        }
    }

    // per-thread argmax over its 20 channels (first-max semantics)
    float m = acc[0]; int mi = 0;
#pragma unroll
    for (int j = 1; j < 20; ++j)
        if (acc[j] > m) { m = acc[j]; mi = j; }
    mi += oc0;

    __syncthreads();
    rm[wv][lane] = m; ri[wv][lane] = mi;
    __syncthreads();
    if (wv == 0) {
        float bm = rm[0][lane]; int bi = ri[0][lane];
#pragma unroll
        for (int v = 1; v < 4; ++v) {
            float om = rm[v][lane]; int oi = ri[v][lane];
            if (om > bm) { bm = om; bi = oi; }   // ascending oc order keeps first max
        }
        int a = a0 + lane;
        if (a < A) {
            max_s[b * A_TOT + a_off + a] = 1.0f / (1.0f + expf(-bm));
            cls_id[b * A_TOT + a_off + a] = bi;
        }
    }
}

// -------- Kernel 2: top-100 per batch (jax.lax.top_k semantics) --------
__global__ __launch_bounds__(1024) void topk_kernel(
    const float* __restrict__ max_s, // [BS][A_TOT]
    const int* __restrict__ cls_id,  // [BS][A_TOT]
    float* __restrict__ out,
    int* __restrict__ top_idx)       // [BS][MAX_DET]
{
    int b = blockIdx.x;
    int tid = threadIdx.x;

    unsigned long long key[9];
#pragma unroll
    for (int i = 0; i < 9; ++i) {
        int a = tid + i * 1024;
        if (a < A_TOT) {
            unsigned u = __float_as_uint(max_s[b * A_TOT + a]); // sigmoid >= 0 -> monotone bits
            key[i] = ((unsigned long long)u << 32) | (unsigned)(0x7FFFFFFF - a);
        } else {
            key[i] = 0ull;
        }
    }

    __shared__ unsigned long long warp_max[16];
    __shared__ unsigned long long winner;

    int cnt = 0;
    for (int k = 0; k < MAX_DET; ++k) {
        unsigned long long best = key[0];
#pragma unroll
        for (int i = 1; i < 9; ++i) best = ullmax(best, key[i]);
        for (int off = 32; off > 0; off >>= 1)
            best = ullmax(best, __shfl_down(best, off, 64));
        if ((tid & 63) == 0) warp_max[tid >> 6] = best;
        __syncthreads();
        if (tid < 16) {
            unsigned long long v = warp_max[tid];
            for (int off = 8; off > 0; off >>= 1)
                v = ullmax(v, __shfl_down(v, off, 16));
            if (tid == 0) winner = v;
        }
        __syncthreads();
        unsigned long long wk = winner;
#pragma unroll
        for (int i = 0; i < 9; ++i)
            if (key[i] == wk) key[i] = 0ull;
        if (tid == 0) {
            float sc = __uint_as_float((unsigned)(wk >> 32));
            int a = 0x7FFFFFFF - (int)(wk & 0xFFFFFFFFull);
            out[OUT_SCORE + b * MAX_DET + k] = sc;
            out[OUT_CLASS + b * MAX_DET + k] = (float)cls_id[b * A_TOT + a];
            top_idx[b * MAX_DET + k] = a;
            if (sc > 0.25f) cnt++;
        }
        __syncthreads();
    }
    if (tid == 0) out[OUT_NUM + b] = (float)cnt;
}

// -------- Kernel 3: decode box + kpts for selected anchors only --------
__global__ __launch_bounds__(128) void decode_kernel(
    const float* __restrict__ x0, const float* __restrict__ x1, const float* __restrict__ x2,
    const float* __restrict__ w2_0, const float* __restrict__ b2_0,
    const float* __restrict__ w2_1, const float* __restrict__ b2_1,
    const float* __restrict__ w2_2, const float* __restrict__ b2_2,
    const float* __restrict__ w4_0, const float* __restrict__ b4_0,
    const float* __restrict__ w4_1, const float* __restrict__ b4_1,
    const float* __restrict__ w4_2, const float* __restrict__ b4_2,
    const int* __restrict__ top_idx,
    float* __restrict__ out)
{
    int b = blockIdx.y;
    int k = blockIdx.x;
    int a = top_idx[b * MAX_DET + k];

    const float* x; const float* w2; const float* bb2; const float* w4; const float* bb4;
    int C, A, W, a_local; float stride;
    if (a < 6400)      { x = x0; C = 128; A = 6400; W = 80; stride = 8.0f;  a_local = a;        w2 = w2_0; bb2 = b2_0; w4 = w4_0; bb4 = b4_0; }
    else if (a < 8000) { x = x1; C = 256; A = 1600; W = 40; stride = 16.0f; a_local = a - 6400; w2 = w2_1; bb2 = b2_1; w4 = w4_1; bb4 = b4_1; }
    else               { x = x2; C = 512; A = 400;  W = 20; stride = 32.0f; a_local = a - 8000; w2 = w2_2; bb2 = b2_2; w4 = w4_2; bb4 = b4_2; }

    __shared__ float fs[512];
    __shared__ float logits[64];
    __shared__ float kraw[NK];
    __shared__ float dist[4];

    int t = threadIdx.x;
    for (int c = t; c < C; c += 128)
        fs[c] = x[((long)b * C + c) * A + a_local];
    __syncthreads();

    if (t < 64 + NK) {
        const float* wrow; float acc;
        if (t < 64) { wrow = w2 + t * C; acc = bb2[t]; }
        else        { wrow = w4 + (t - 64) * C; acc = bb4[t - 64]; }
        for (int c = 0; c < C; ++c) acc = fmaf(wrow[c], fs[c], acc);
        if (t < 64) logits[t] = acc;
        else        kraw[t - 64] = acc;
    }
    __syncthreads();

    if (t < 4) {
        float mx = logits[t * 16];
#pragma unroll
        for (int r = 1; r < 16; ++r) mx = fmaxf(mx, logits[t * 16 + r]);
        float se = 0.0f, sw = 0.0f;
#pragma unroll
        for (int r = 0; r < 16; ++r) {
            float e = expf(logits[t * 16 + r] - mx);
            se += e; sw += e * (float)r;
        }
        dist[t] = sw / se;
    }
    __syncthreads();

    float ax = (float)(a_local % W) + 0.5f;
    float ay = (float)(a_local / W) + 0.5f;

    if (t == 0) {
        float x1c = ax - dist[0], y1c = ay - dist[1];
        float x2c = ax + dist[2], y2c = ay + dist[3];
        float* ob = out + OUT_BOX + ((long)b * MAX_DET + k) * 4;
        ob[0] = (x1c + x2c) * 0.5f * stride;
        ob[1] = (y1c + y2c) * 0.5f * stride;
        ob[2] = (x2c - x1c) * stride;
        ob[3] = (y2c - y1c) * stride;
    }
    if (t < 17) {
        float vx = kraw[t * 3], vy = kraw[t * 3 + 1], vv = kraw[t * 3 + 2];
        float gx = ax - 0.5f, gy = ay - 0.5f;
        float* ok = out + OUT_KPT + (((long)b * MAX_DET + k) * 17 + t) * 3;
        ok[0] = (vx * 2.0f + gx) * stride;
        ok[1] = (vy * 2.0f + gy) * stride;
        ok[2] = 1.0f / (1.0f + expf(-vv));
    }
}

extern "C" void kernel_launch(void* const* d_in, const int* in_sizes, int n_in,
                              void* d_out, int out_size, void* d_ws, size_t ws_size,
                              hipStream_t stream) {
    const float* x0 = (const float*)d_in[0];
    const float* x1 = (const float*)d_in[1];
    const float* x2 = (const float*)d_in[2];
    // cv2 (box): idx 3..8, cv3 (cls): 9..14, cv4 (kpt): 15..20
    const float* w2[3] = {(const float*)d_in[3], (const float*)d_in[5], (const float*)d_in[7]};
    const float* b2[3] = {(const float*)d_in[4], (const float*)d_in[6], (const float*)d_in[8]};
    const float* w3[3] = {(const float*)d_in[9], (const float*)d_in[11], (const float*)d_in[13]};
    const float* b3[3] = {(const float*)d_in[10], (const float*)d_in[12], (const float*)d_in[14]};
    const float* w4[3] = {(const float*)d_in[15], (const float*)d_in[17], (const float*)d_in[19]};
    const float* b4[3] = {(const float*)d_in[16], (const float*)d_in[18], (const float*)d_in[20]};

    float* out = (float*)d_out;

    float* ws_maxs = (float*)d_ws;                    // [16][8400]
    int* ws_cls = (int*)(ws_maxs + BS * A_TOT);       // [16][8400]
    int* ws_top = (int*)(ws_cls + BS * A_TOT);        // [16][100]

    // scores per level (64 anchors per block)
    {
        dim3 g0(6400 / 64, BS);
        scores_kernel<128><<<g0, 256, 0, stream>>>(x0, w3[0], b3[0], ws_maxs, ws_cls, 6400, 0);
        dim3 g1(1600 / 64, BS);
        scores_kernel<256><<<g1, 256, 0, stream>>>(x1, w3[1], b3[1], ws_maxs, ws_cls, 1600, 6400);
        dim3 g2((400 + 63) / 64, BS);
        scores_kernel<512><<<g2, 256, 0, stream>>>(x2, w3[2], b3[2], ws_maxs, ws_cls, 400, 8000);
    }
    // top-k
    topk_kernel<<<dim3(BS), 1024, 0, stream>>>(ws_maxs, ws_cls, out, ws_top);
    // decode selected
    decode_kernel<<<dim3(MAX_DET, BS), 128, 0, stream>>>(
        x0, x1, x2,
        w2[0], b2[0], w2[1], b2[1], w2[2], b2[2],
        w4[0], b4[0], w4[1], b4[1], w4[2], b4[2],
        ws_top, out);
}

// Round 3
// 447.443 us; speedup vs baseline: 3.5023x; 1.2128x over previous
//
#include <hip/hip_runtime.h>
#include <hip/hip_bf16.h>

#define NC 80
#define NK 51
#define REG_MAX 16
#define MAX_DET 100
#define A_TOT 8400
#define BS 16

// out layout (float32): num[16] | boxes[16*100*4] | scores[16*100] | classes[16*100] | kpts[16*100*17*3]
#define OUT_NUM 0
#define OUT_BOX 16
#define OUT_SCORE (16 + 16*MAX_DET*4)
#define OUT_CLASS (OUT_SCORE + 16*MAX_DET)
#define OUT_KPT (OUT_CLASS + 16*MAX_DET)

static __device__ __forceinline__ unsigned long long mk_key(unsigned u, int a) {
    return ((unsigned long long)u << 32) | (unsigned)(0x7FFFFFFF - a);
}

// -------- Kernel 1: class scores (sigmoid-max + argmax) per anchor --------
// Block: 256 threads = 64 anchors (lane) x 4 waves (20 output channels each).
template <int C>
__global__ __launch_bounds__(256) void scores_kernel(
    const float* __restrict__ x,    // [BS][C][A]
    const float* __restrict__ w,    // [NC][C]
    const float* __restrict__ bias, // [NC]
    float* __restrict__ max_s,      // [BS][A_TOT]
    int* __restrict__ cls_id,       // [BS][A_TOT]
    int A, int a_off)
{
    constexpr int CHUNK = 128;
    __shared__ float fs[CHUNK * 64];      // 32 KB
    __shared__ float rm[4][64];
    __shared__ int   ri[4][64];

    int b = blockIdx.y;
    int a0 = blockIdx.x * 64;
    int t = threadIdx.x;
    int lane = t & 63;
    int wv = __builtin_amdgcn_readfirstlane(t >> 6);   // 0..3, wave-uniform
    int oc0 = wv * 20;
    const float* wbase = w + oc0 * C;

    float acc[20];
#pragma unroll
    for (int j = 0; j < 20; ++j) acc[j] = bias[oc0 + j];

    const float* xb = x + (long)b * C * A;

    for (int c0 = 0; c0 < C; c0 += CHUNK) {
        __syncthreads();
#pragma unroll
        for (int i = 0; i < 8; ++i) {            // 2048 float4 / 256 threads
            int idx = t + i * 256;
            int c = idx >> 4;
            int q = (idx & 15) * 4;
            int aa = a0 + q;
            if (aa > A - 4) aa = A - 4;
            float4 v = *(const float4*)(xb + (long)(c0 + c) * A + aa);
            *(float4*)(&fs[c * 64 + q]) = v;
        }
        __syncthreads();

#pragma unroll 1
        for (int c = 0; c < CHUNK; c += 4) {
            float fv0 = fs[(c + 0) * 64 + lane];
            float fv1 = fs[(c + 1) * 64 + lane];
            float fv2 = fs[(c + 2) * 64 + lane];
            float fv3 = fs[(c + 3) * 64 + lane];
#pragma unroll
            for (int j = 0; j < 20; ++j) {
                float w0 = wbase[j * C + c0 + c + 0];
                float w1 = wbase[j * C + c0 + c + 1];
                float w2 = wbase[j * C + c0 + c + 2];
                float w3 = wbase[j * C + c0 + c + 3];
                acc[j] = fmaf(w0, fv0, acc[j]);
                acc[j] = fmaf(w1, fv1, acc[j]);
                acc[j] = fmaf(w2, fv2, acc[j]);
                acc[j] = fmaf(w3, fv3, acc[j]);
            }
        }
    }

    float m = acc[0]; int mi = 0;
#pragma unroll
    for (int j = 1; j < 20; ++j)
        if (acc[j] > m) { m = acc[j]; mi = j; }
    mi += oc0;

    __syncthreads();
    rm[wv][lane] = m; ri[wv][lane] = mi;
    __syncthreads();
    if (wv == 0) {
        float bm = rm[0][lane]; int bi = ri[0][lane];
#pragma unroll
        for (int v = 1; v < 4; ++v) {
            float om = rm[v][lane]; int oi = ri[v][lane];
            if (om > bm) { bm = om; bi = oi; }
        }
        int a = a0 + lane;
        if (a < A) {
            max_s[b * A_TOT + a_off + a] = 1.0f / (1.0f + expf(-bm));
            cls_id[b * A_TOT + a_off + a] = bi;
        }
    }
}

// -------- Kernel 2: exact top-100 per batch via radix select --------
__global__ __launch_bounds__(1024) void topk_kernel(
    const float* __restrict__ max_s, // [BS][A_TOT]
    const int* __restrict__ cls_id,  // [BS][A_TOT]
    float* __restrict__ out,
    int* __restrict__ top_idx)       // [BS][MAX_DET]
{
    int b = blockIdx.x;
    int t = threadIdx.x;
    int wv = t >> 6;

    __shared__ unsigned hist[16 * 256];          // per-wave histograms, 16 KB
    __shared__ unsigned suffix[256];
    __shared__ int tieIdx[A_TOT];                // 33.6 KB
    __shared__ unsigned long long highKeys[128];
    __shared__ unsigned long long finalKeys[128];
    __shared__ int wmin[16];
    __shared__ unsigned s_prefix;
    __shared__ int s_k, s_selD, s_nHigh, s_nTie, s_cnt, s_bcast;

    // load score bits (sigmoid >= 0 -> IEEE bits monotone)
    unsigned u[9];
    bool val[9];
#pragma unroll
    for (int i = 0; i < 9; ++i) {
        int a = t + i * 1024;
        val[i] = (a < A_TOT);
        u[i] = val[i] ? __float_as_uint(max_s[b * A_TOT + a]) : 0u;
    }

    if (t == 0) { s_prefix = 0; s_k = MAX_DET; s_nHigh = 0; s_nTie = 0; s_cnt = 0; }

    // ---- 4 passes of 8-bit radix select (find exact bits of 100th score) ----
    for (int pass = 0; pass < 4; ++pass) {
#pragma unroll
        for (int j = 0; j < 4; ++j) hist[t + j * 1024] = 0;
        if (t == 0) s_selD = 0;
        __syncthreads();

        unsigned pre = s_prefix;
        int k = s_k;
        int shHi = 32 - 8 * pass;   // only used when pass > 0
        int shD = 24 - 8 * pass;
#pragma unroll
        for (int i = 0; i < 9; ++i) {
            if (val[i]) {
                bool cand = (pass == 0) ? true : ((u[i] >> shHi) == pre);
                if (cand)
                    atomicAdd(&hist[(wv << 8) + ((u[i] >> shD) & 0xFF)], 1u);
            }
        }
        __syncthreads();

        if (t < 256) {
            unsigned s = 0;
#pragma unroll
            for (int w = 0; w < 16; ++w) s += hist[(w << 8) + t];
            suffix[t] = s;
        }
        __syncthreads();
        // suffix sums (Hillis-Steele, 8 rounds)
        for (int off = 1; off < 256; off <<= 1) {
            unsigned v = 0;
            if (t < 256) v = suffix[t] + ((t + off < 256) ? suffix[t + off] : 0u);
            __syncthreads();
            if (t < 256) suffix[t] = v;
            __syncthreads();
        }
        if (t < 256 && suffix[t] >= (unsigned)k) atomicMax(&s_selD, t);
        __syncthreads();
        if (t == 0) {
            int d = s_selD;
            s_k = k - ((d < 255) ? (int)suffix[d + 1] : 0);
            s_prefix = (pre << 8) | (unsigned)d;
        }
        __syncthreads();
    }

    unsigned cut = s_prefix;      // exact bits of the 100th-largest score
    int r = s_k;                  // how many == cut make the top-100

    // ---- compact: strictly-greater keys + tie indices ----
#pragma unroll
    for (int i = 0; i < 9; ++i) {
        if (val[i]) {
            int a = t + i * 1024;
            if (u[i] > cut) {
                int p = atomicAdd(&s_nHigh, 1);
                highKeys[p] = mk_key(u[i], a);
            } else if (u[i] == cut) {
                int p = atomicAdd(&s_nTie, 1);
                tieIdx[p] = a;
            }
        }
    }
    __syncthreads();
    int m = s_nHigh;
    int nt = s_nTie;

    if (t < 128) finalKeys[t] = 0ull;
    __syncthreads();
    if (t < m) finalKeys[t] = highKeys[t];

    if (nt == r) {
        if (t < nt) finalKeys[m + t] = mk_key(cut, tieIdx[t]);
        __syncthreads();
    } else {
        __syncthreads();
        // rare path: pick r smallest tie indices iteratively
        for (int j = 0; j < r; ++j) {
            int mn = 0x7FFFFFFF;
            for (int p = t; p < nt; p += 1024) mn = min(mn, tieIdx[p]);
            for (int off = 32; off > 0; off >>= 1) mn = min(mn, __shfl_down(mn, off, 64));
            if ((t & 63) == 0) wmin[wv] = mn;
            __syncthreads();
            if (t == 0) {
                int v = wmin[0];
#pragma unroll
                for (int w = 1; w < 16; ++w) v = min(v, wmin[w]);
                s_bcast = v;
                finalKeys[m + j] = mk_key(cut, v);
            }
            __syncthreads();
            int v = s_bcast;
            for (int p = t; p < nt; p += 1024)
                if (tieIdx[p] == v) tieIdx[p] = 0x7FFFFFFF;
            __syncthreads();
        }
    }

    // ---- bitonic sort 128 keys descending ----
    for (int ksz = 2; ksz <= 128; ksz <<= 1) {
        for (int j = ksz >> 1; j > 0; j >>= 1) {
            if (t < 128) {
                int ixj = t ^ j;
                if (ixj > t) {
                    bool desc = ((t & ksz) == 0);
                    unsigned long long x = finalKeys[t], y = finalKeys[ixj];
                    bool sw = desc ? (x < y) : (x > y);
                    if (sw) { finalKeys[t] = y; finalKeys[ixj] = x; }
                }
            }
            __syncthreads();
        }
    }

    // ---- write outputs ----
    if (t < MAX_DET) {
        unsigned long long kk = finalKeys[t];
        float sc = __uint_as_float((unsigned)(kk >> 32));
        int a = 0x7FFFFFFF - (int)(kk & 0xFFFFFFFFull);
        out[OUT_SCORE + b * MAX_DET + t] = sc;
        out[OUT_CLASS + b * MAX_DET + t] = (float)cls_id[b * A_TOT + a];
        top_idx[b * MAX_DET + t] = a;
        if (sc > 0.25f) atomicAdd(&s_cnt, 1);
    }
    __syncthreads();
    if (t == 0) out[OUT_NUM + b] = (float)s_cnt;
}

// -------- Kernel 3: decode box + kpts for selected anchors only --------
__global__ __launch_bounds__(128) void decode_kernel(
    const float* __restrict__ x0, const float* __restrict__ x1, const float* __restrict__ x2,
    const float* __restrict__ w2_0, const float* __restrict__ b2_0,
    const float* __restrict__ w2_1, const float* __restrict__ b2_1,
    const float* __restrict__ w2_2, const float* __restrict__ b2_2,
    const float* __restrict__ w4_0, const float* __restrict__ b4_0,
    const float* __restrict__ w4_1, const float* __restrict__ b4_1,
    const float* __restrict__ w4_2, const float* __restrict__ b4_2,
    const int* __restrict__ top_idx,
    float* __restrict__ out)
{
    int b = blockIdx.y;
    int k = blockIdx.x;
    int a = top_idx[b * MAX_DET + k];

    const float* x; const float* w2; const float* bb2; const float* w4; const float* bb4;
    int C, A, W, a_local; float stride;
    if (a < 6400)      { x = x0; C = 128; A = 6400; W = 80; stride = 8.0f;  a_local = a;        w2 = w2_0; bb2 = b2_0; w4 = w4_0; bb4 = b4_0; }
    else if (a < 8000) { x = x1; C = 256; A = 1600; W = 40; stride = 16.0f; a_local = a - 6400; w2 = w2_1; bb2 = b2_1; w4 = w4_1; bb4 = b4_1; }
    else               { x = x2; C = 512; A = 400;  W = 20; stride = 32.0f; a_local = a - 8000; w2 = w2_2; bb2 = b2_2; w4 = w4_2; bb4 = b4_2; }

    __shared__ float fs[512];
    __shared__ float logits[64];
    __shared__ float kraw[NK];
    __shared__ float dist[4];

    int t = threadIdx.x;
    for (int c = t; c < C; c += 128)
        fs[c] = x[((long)b * C + c) * A + a_local];
    __syncthreads();

    if (t < 64 + NK) {
        const float* wrow; float acc;
        if (t < 64) { wrow = w2 + t * C; acc = bb2[t]; }
        else        { wrow = w4 + (t - 64) * C; acc = bb4[t - 64]; }
        for (int c = 0; c < C; ++c) acc = fmaf(wrow[c], fs[c], acc);
        if (t < 64) logits[t] = acc;
        else        kraw[t - 64] = acc;
    }
    __syncthreads();

    if (t < 4) {
        float mx = logits[t * 16];
#pragma unroll
        for (int r = 1; r < 16; ++r) mx = fmaxf(mx, logits[t * 16 + r]);
        float se = 0.0f, sw = 0.0f;
#pragma unroll
        for (int r = 0; r < 16; ++r) {
            float e = expf(logits[t * 16 + r] - mx);
            se += e; sw += e * (float)r;
        }
        dist[t] = sw / se;
    }
    __syncthreads();

    float ax = (float)(a_local % W) + 0.5f;
    float ay = (float)(a_local / W) + 0.5f;

    if (t == 0) {
        float x1c = ax - dist[0], y1c = ay - dist[1];
        float x2c = ax + dist[2], y2c = ay + dist[3];
        float* ob = out + OUT_BOX + ((long)b * MAX_DET + k) * 4;
        ob[0] = (x1c + x2c) * 0.5f * stride;
        ob[1] = (y1c + y2c) * 0.5f * stride;
        ob[2] = (x2c - x1c) * stride;
        ob[3] = (y2c - y1c) * stride;
    }
    if (t < 17) {
        float vx = kraw[t * 3], vy = kraw[t * 3 + 1], vv = kraw[t * 3 + 2];
        float gx = ax - 0.5f, gy = ay - 0.5f;
        float* ok = out + OUT_KPT + (((long)b * MAX_DET + k) * 17 + t) * 3;
        ok[0] = (vx * 2.0f + gx) * stride;
        ok[1] = (vy * 2.0f + gy) * stride;
        ok[2] = 1.0f / (1.0f + expf(-vv));
    }
}

extern "C" void kernel_launch(void* const* d_in, const int* in_sizes, int n_in,
                              void* d_out, int out_size, void* d_ws, size_t ws_size,
                              hipStream_t stream) {
    const float* x0 = (const float*)d_in[0];
    const float* x1 = (const float*)d_in[1];
    const float* x2 = (const float*)d_in[2];
    const float* w2[3] = {(const float*)d_in[3], (const float*)d_in[5], (const float*)d_in[7]};
    const float* b2[3] = {(const float*)d_in[4], (const float*)d_in[6], (const float*)d_in[8]};
    const float* w3[3] = {(const float*)d_in[9], (const float*)d_in[11], (const float*)d_in[13]};
    const float* b3[3] = {(const float*)d_in[10], (const float*)d_in[12], (const float*)d_in[14]};
    const float* w4[3] = {(const float*)d_in[15], (const float*)d_in[17], (const float*)d_in[19]};
    const float* b4[3] = {(const float*)d_in[16], (const float*)d_in[18], (const float*)d_in[20]};

    float* out = (float*)d_out;

    float* ws_maxs = (float*)d_ws;                    // [16][8400]
    int* ws_cls = (int*)(ws_maxs + BS * A_TOT);       // [16][8400]
    int* ws_top = (int*)(ws_cls + BS * A_TOT);        // [16][100]

    {
        dim3 g0(6400 / 64, BS);
        scores_kernel<128><<<g0, 256, 0, stream>>>(x0, w3[0], b3[0], ws_maxs, ws_cls, 6400, 0);
        dim3 g1(1600 / 64, BS);
        scores_kernel<256><<<g1, 256, 0, stream>>>(x1, w3[1], b3[1], ws_maxs, ws_cls, 1600, 6400);
        dim3 g2((400 + 63) / 64, BS);
        scores_kernel<512><<<g2, 256, 0, stream>>>(x2, w3[2], b3[2], ws_maxs, ws_cls, 400, 8000);
    }
    topk_kernel<<<dim3(BS), 1024, 0, stream>>>(ws_maxs, ws_cls, out, ws_top);
    decode_kernel<<<dim3(MAX_DET, BS), 128, 0, stream>>>(
        x0, x1, x2,
        w2[0], b2[0], w2[1], b2[1], w2[2], b2[2],
        w4[0], b4[0], w4[1], b4[1], w4[2], b4[2],
        ws_top, out);
}

// Round 4
// 302.224 us; speedup vs baseline: 5.1852x; 1.4805x over previous
//
#include <hip/hip_runtime.h>
#include <hip/hip_bf16.h>

#define NC 80
#define NK 51
#define REG_MAX 16
#define MAX_DET 100
#define A_TOT 8400
#define BS 16

// out layout (float32): num[16] | boxes[16*100*4] | scores[16*100] | classes[16*100] | kpts[16*100*17*3]
#define OUT_NUM 0
#define OUT_BOX 16
#define OUT_SCORE (16 + 16*MAX_DET*4)
#define OUT_CLASS (OUT_SCORE + 16*MAX_DET)
#define OUT_KPT (OUT_CLASS + 16*MAX_DET)

static __device__ __forceinline__ unsigned long long mk_key(unsigned u, int a) {
    return ((unsigned long long)u << 32) | (unsigned)(0x7FFFFFFF - a);
}

// -------- Kernel 1: fused class scores over all 3 levels --------
// Block: 256 threads = 4 waves (20 ocs each) x 64 lanes; 128 anchors/block
// (2 per thread). Weights staged in LDS per 32-channel chunk (broadcast
// ds_read_b128 -> no scalar-cache thrash); features in LDS [c][a].
__global__ __launch_bounds__(256) void scores_fused(
    const float* __restrict__ x0, const float* __restrict__ x1, const float* __restrict__ x2,
    const float* __restrict__ w0, const float* __restrict__ w1, const float* __restrict__ w2,
    const float* __restrict__ bias0, const float* __restrict__ bias1, const float* __restrict__ bias2,
    float* __restrict__ max_s,       // [BS][A_TOT]
    int* __restrict__ cls_id)        // [BS][A_TOT]
{
    __shared__ float fs[32 * 128];   // 16 KB  [c][a]
    __shared__ float wsh[80 * 32];   // 10 KB  [oc][c]
    __shared__ float rm[4][128];
    __shared__ int   ri[4][128];

    int bid = blockIdx.x;
    const float *x, *w, *bias; int C, A, a_off, b, tile;
    if (bid < 64) {                 // level 2 first: longest serial work, overlap with rest
        x = x2; w = w2; bias = bias2; C = 512; A = 400; a_off = 8000;
        b = bid >> 2; tile = bid & 3;
    } else if (bid < 272) {         // level 1: 16 b x 13 tiles
        int r = bid - 64;
        x = x1; w = w1; bias = bias1; C = 256; A = 1600; a_off = 6400;
        b = r / 13; tile = r - b * 13;
    } else {                        // level 0: 16 b x 50 tiles
        int r = bid - 272;
        x = x0; w = w0; bias = bias0; C = 128; A = 6400; a_off = 0;
        b = r / 50; tile = r - b * 50;
    }
    int a0 = tile * 128;

    int t = threadIdx.x;
    int lane = t & 63;
    int wv = t >> 6;
    int oc0 = wv * 20;

    float acc0[20], acc1[20];
#pragma unroll
    for (int j = 0; j < 20; ++j) { float bv = bias[oc0 + j]; acc0[j] = bv; acc1[j] = bv; }

    const float* xb = x + (long)b * C * A;
    int nchunk = C >> 5;

    for (int kc = 0; kc < nchunk; ++kc) {
        __syncthreads();
        // stage features: 32 channels x 128 anchors (1024 float4)
#pragma unroll
        for (int i = 0; i < 4; ++i) {
            int idx = t + i * 256;
            int c = idx >> 5;
            int q = (idx & 31) * 4;
            int aa = a0 + q; if (aa > A - 4) aa = A - 4;
            float4 v = *(const float4*)(xb + (long)(kc * 32 + c) * A + aa);
            *(float4*)(&fs[c * 128 + q]) = v;
        }
        // stage weights: 80 ocs x 32 channels (640 float4)
#pragma unroll
        for (int i = 0; i < 3; ++i) {
            int idx = t + i * 256;
            if (idx < 640) {
                int oc = idx >> 3;
                int q = (idx & 7) * 4;
                float4 v = *(const float4*)(w + oc * C + kc * 32 + q);
                *(float4*)(&wsh[oc * 32 + q]) = v;
            }
        }
        __syncthreads();

#pragma unroll 1
        for (int c4 = 0; c4 < 32; c4 += 4) {
            float fa[4], fb[4];
#pragma unroll
            for (int cc = 0; cc < 4; ++cc) {
                fa[cc] = fs[(c4 + cc) * 128 + lane];
                fb[cc] = fs[(c4 + cc) * 128 + lane + 64];
            }
#pragma unroll
            for (int j = 0; j < 20; ++j) {
                float4 w4 = *(const float4*)(&wsh[(oc0 + j) * 32 + c4]);  // broadcast
                acc0[j] = fmaf(w4.x, fa[0], acc0[j]);
                acc0[j] = fmaf(w4.y, fa[1], acc0[j]);
                acc0[j] = fmaf(w4.z, fa[2], acc0[j]);
                acc0[j] = fmaf(w4.w, fa[3], acc0[j]);
                acc1[j] = fmaf(w4.x, fb[0], acc1[j]);
                acc1[j] = fmaf(w4.y, fb[1], acc1[j]);
                acc1[j] = fmaf(w4.z, fb[2], acc1[j]);
                acc1[j] = fmaf(w4.w, fb[3], acc1[j]);
            }
        }
    }

    // per-anchor argmax over this thread's 20 ocs (first-max semantics)
    float m0 = acc0[0], m1 = acc1[0]; int i0 = 0, i1 = 0;
#pragma unroll
    for (int j = 1; j < 20; ++j) {
        if (acc0[j] > m0) { m0 = acc0[j]; i0 = j; }
        if (acc1[j] > m1) { m1 = acc1[j]; i1 = j; }
    }
    i0 += oc0; i1 += oc0;

    rm[wv][lane] = m0;      ri[wv][lane] = i0;
    rm[wv][lane + 64] = m1; ri[wv][lane + 64] = i1;
    __syncthreads();
    if (wv == 0) {
#pragma unroll
        for (int p = 0; p < 2; ++p) {
            int a = lane + p * 64;
            float bm = rm[0][a]; int bi = ri[0][a];
#pragma unroll
            for (int v = 1; v < 4; ++v) {
                float om = rm[v][a];
                if (om > bm) { bm = om; bi = ri[v][a]; }  // ascending oc keeps first max
            }
            int ga = a0 + a;
            if (ga < A) {
                max_s[b * A_TOT + a_off + ga] = 1.0f / (1.0f + expf(-bm));
                cls_id[b * A_TOT + a_off + ga] = bi;
            }
        }
    }
}

// -------- Kernel 2: exact top-100 per batch via radix select --------
__global__ __launch_bounds__(1024) void topk_kernel(
    const float* __restrict__ max_s, // [BS][A_TOT]
    const int* __restrict__ cls_id,  // [BS][A_TOT]
    float* __restrict__ out,
    int* __restrict__ top_idx)       // [BS][MAX_DET]
{
    int b = blockIdx.x;
    int t = threadIdx.x;
    int wv = t >> 6;

    __shared__ unsigned hist[16 * 256];          // per-wave histograms, 16 KB
    __shared__ unsigned suffix[256];
    __shared__ int tieIdx[A_TOT];                // 33.6 KB
    __shared__ unsigned long long highKeys[128];
    __shared__ unsigned long long finalKeys[128];
    __shared__ int wmin[16];
    __shared__ unsigned s_prefix;
    __shared__ int s_k, s_selD, s_nHigh, s_nTie, s_cnt, s_bcast;

    unsigned u[9];
    bool val[9];
#pragma unroll
    for (int i = 0; i < 9; ++i) {
        int a = t + i * 1024;
        val[i] = (a < A_TOT);
        u[i] = val[i] ? __float_as_uint(max_s[b * A_TOT + a]) : 0u;
    }

    if (t == 0) { s_prefix = 0; s_k = MAX_DET; s_nHigh = 0; s_nTie = 0; s_cnt = 0; }

    for (int pass = 0; pass < 4; ++pass) {
#pragma unroll
        for (int j = 0; j < 4; ++j) hist[t + j * 1024] = 0;
        if (t == 0) s_selD = 0;
        __syncthreads();

        unsigned pre = s_prefix;
        int k = s_k;
        int shHi = 32 - 8 * pass;
        int shD = 24 - 8 * pass;
#pragma unroll
        for (int i = 0; i < 9; ++i) {
            if (val[i]) {
                bool cand = (pass == 0) ? true : ((u[i] >> shHi) == pre);
                if (cand)
                    atomicAdd(&hist[(wv << 8) + ((u[i] >> shD) & 0xFF)], 1u);
            }
        }
        __syncthreads();

        if (t < 256) {
            unsigned s = 0;
#pragma unroll
            for (int w = 0; w < 16; ++w) s += hist[(w << 8) + t];
            suffix[t] = s;
        }
        __syncthreads();
        for (int off = 1; off < 256; off <<= 1) {
            unsigned v = 0;
            if (t < 256) v = suffix[t] + ((t + off < 256) ? suffix[t + off] : 0u);
            __syncthreads();
            if (t < 256) suffix[t] = v;
            __syncthreads();
        }
        if (t < 256 && suffix[t] >= (unsigned)k) atomicMax(&s_selD, t);
        __syncthreads();
        if (t == 0) {
            int d = s_selD;
            s_k = k - ((d < 255) ? (int)suffix[d + 1] : 0);
            s_prefix = (pre << 8) | (unsigned)d;
        }
        __syncthreads();
    }

    unsigned cut = s_prefix;
    int r = s_k;

#pragma unroll
    for (int i = 0; i < 9; ++i) {
        if (val[i]) {
            int a = t + i * 1024;
            if (u[i] > cut) {
                int p = atomicAdd(&s_nHigh, 1);
                highKeys[p] = mk_key(u[i], a);
            } else if (u[i] == cut) {
                int p = atomicAdd(&s_nTie, 1);
                tieIdx[p] = a;
            }
        }
    }
    __syncthreads();
    int m = s_nHigh;
    int nt = s_nTie;

    if (t < 128) finalKeys[t] = 0ull;
    __syncthreads();
    if (t < m) finalKeys[t] = highKeys[t];

    if (nt == r) {
        if (t < nt) finalKeys[m + t] = mk_key(cut, tieIdx[t]);
        __syncthreads();
    } else {
        __syncthreads();
        for (int j = 0; j < r; ++j) {
            int mn = 0x7FFFFFFF;
            for (int p = t; p < nt; p += 1024) mn = min(mn, tieIdx[p]);
            for (int off = 32; off > 0; off >>= 1) mn = min(mn, __shfl_down(mn, off, 64));
            if ((t & 63) == 0) wmin[wv] = mn;
            __syncthreads();
            if (t == 0) {
                int v = wmin[0];
#pragma unroll
                for (int w = 1; w < 16; ++w) v = min(v, wmin[w]);
                s_bcast = v;
                finalKeys[m + j] = mk_key(cut, v);
            }
            __syncthreads();
            int v = s_bcast;
            for (int p = t; p < nt; p += 1024)
                if (tieIdx[p] == v) tieIdx[p] = 0x7FFFFFFF;
            __syncthreads();
        }
    }

    for (int ksz = 2; ksz <= 128; ksz <<= 1) {
        for (int j = ksz >> 1; j > 0; j >>= 1) {
            if (t < 128) {
                int ixj = t ^ j;
                if (ixj > t) {
                    bool desc = ((t & ksz) == 0);
                    unsigned long long x = finalKeys[t], y = finalKeys[ixj];
                    bool sw = desc ? (x < y) : (x > y);
                    if (sw) { finalKeys[t] = y; finalKeys[ixj] = x; }
                }
            }
            __syncthreads();
        }
    }

    if (t < MAX_DET) {
        unsigned long long kk = finalKeys[t];
        float sc = __uint_as_float((unsigned)(kk >> 32));
        int a = 0x7FFFFFFF - (int)(kk & 0xFFFFFFFFull);
        out[OUT_SCORE + b * MAX_DET + t] = sc;
        out[OUT_CLASS + b * MAX_DET + t] = (float)cls_id[b * A_TOT + a];
        top_idx[b * MAX_DET + t] = a;
        if (sc > 0.25f) atomicAdd(&s_cnt, 1);
    }
    __syncthreads();
    if (t == 0) out[OUT_NUM + b] = (float)s_cnt;
}

// -------- Kernel 3: decode box + kpts for selected anchors only --------
__global__ __launch_bounds__(128) void decode_kernel(
    const float* __restrict__ x0, const float* __restrict__ x1, const float* __restrict__ x2,
    const float* __restrict__ w2_0, const float* __restrict__ b2_0,
    const float* __restrict__ w2_1, const float* __restrict__ b2_1,
    const float* __restrict__ w2_2, const float* __restrict__ b2_2,
    const float* __restrict__ w4_0, const float* __restrict__ b4_0,
    const float* __restrict__ w4_1, const float* __restrict__ b4_1,
    const float* __restrict__ w4_2, const float* __restrict__ b4_2,
    const int* __restrict__ top_idx,
    float* __restrict__ out)
{
    int b = blockIdx.y;
    int k = blockIdx.x;
    int a = top_idx[b * MAX_DET + k];

    const float* x; const float* w2; const float* bb2; const float* w4; const float* bb4;
    int C, A, W, a_local; float stride;
    if (a < 6400)      { x = x0; C = 128; A = 6400; W = 80; stride = 8.0f;  a_local = a;        w2 = w2_0; bb2 = b2_0; w4 = w4_0; bb4 = b4_0; }
    else if (a < 8000) { x = x1; C = 256; A = 1600; W = 40; stride = 16.0f; a_local = a - 6400; w2 = w2_1; bb2 = b2_1; w4 = w4_1; bb4 = b4_1; }
    else               { x = x2; C = 512; A = 400;  W = 20; stride = 32.0f; a_local = a - 8000; w2 = w2_2; bb2 = b2_2; w4 = w4_2; bb4 = b4_2; }

    __shared__ float fs[512];
    __shared__ float logits[64];
    __shared__ float kraw[NK];
    __shared__ float dist[4];

    int t = threadIdx.x;
    for (int c = t; c < C; c += 128)
        fs[c] = x[((long)b * C + c) * A + a_local];
    __syncthreads();

    if (t < 64 + NK) {
        const float* wrow; float acc;
        if (t < 64) { wrow = w2 + t * C; acc = bb2[t]; }
        else        { wrow = w4 + (t - 64) * C; acc = bb4[t - 64]; }
        for (int c = 0; c < C; ++c) acc = fmaf(wrow[c], fs[c], acc);
        if (t < 64) logits[t] = acc;
        else        kraw[t - 64] = acc;
    }
    __syncthreads();

    if (t < 4) {
        float mx = logits[t * 16];
#pragma unroll
        for (int r = 1; r < 16; ++r) mx = fmaxf(mx, logits[t * 16 + r]);
        float se = 0.0f, sw = 0.0f;
#pragma unroll
        for (int r = 0; r < 16; ++r) {
            float e = expf(logits[t * 16 + r] - mx);
            se += e; sw += e * (float)r;
        }
        dist[t] = sw / se;
    }
    __syncthreads();

    float ax = (float)(a_local % W) + 0.5f;
    float ay = (float)(a_local / W) + 0.5f;

    if (t == 0) {
        float x1c = ax - dist[0], y1c = ay - dist[1];
        float x2c = ax + dist[2], y2c = ay + dist[3];
        float* ob = out + OUT_BOX + ((long)b * MAX_DET + k) * 4;
        ob[0] = (x1c + x2c) * 0.5f * stride;
        ob[1] = (y1c + y2c) * 0.5f * stride;
        ob[2] = (x2c - x1c) * stride;
        ob[3] = (y2c - y1c) * stride;
    }
    if (t < 17) {
        float vx = kraw[t * 3], vy = kraw[t * 3 + 1], vv = kraw[t * 3 + 2];
        float gx = ax - 0.5f, gy = ay - 0.5f;
        float* ok = out + OUT_KPT + (((long)b * MAX_DET + k) * 17 + t) * 3;
        ok[0] = (vx * 2.0f + gx) * stride;
        ok[1] = (vy * 2.0f + gy) * stride;
        ok[2] = 1.0f / (1.0f + expf(-vv));
    }
}

extern "C" void kernel_launch(void* const* d_in, const int* in_sizes, int n_in,
                              void* d_out, int out_size, void* d_ws, size_t ws_size,
                              hipStream_t stream) {
    const float* x0 = (const float*)d_in[0];
    const float* x1 = (const float*)d_in[1];
    const float* x2 = (const float*)d_in[2];
    const float* w2[3] = {(const float*)d_in[3], (const float*)d_in[5], (const float*)d_in[7]};
    const float* b2[3] = {(const float*)d_in[4], (const float*)d_in[6], (const float*)d_in[8]};
    const float* w3[3] = {(const float*)d_in[9], (const float*)d_in[11], (const float*)d_in[13]};
    const float* b3[3] = {(const float*)d_in[10], (const float*)d_in[12], (const float*)d_in[14]};
    const float* w4[3] = {(const float*)d_in[15], (const float*)d_in[17], (const float*)d_in[19]};
    const float* b4[3] = {(const float*)d_in[16], (const float*)d_in[18], (const float*)d_in[20]};

    float* out = (float*)d_out;

    float* ws_maxs = (float*)d_ws;                    // [16][8400]
    int* ws_cls = (int*)(ws_maxs + BS * A_TOT);       // [16][8400]
    int* ws_top = (int*)(ws_cls + BS * A_TOT);        // [16][100]

    // fused scores: 64 (L2) + 208 (L1) + 800 (L0) blocks
    scores_fused<<<dim3(1072), 256, 0, stream>>>(
        x0, x1, x2, w3[0], w3[1], w3[2], b3[0], b3[1], b3[2], ws_maxs, ws_cls);
    topk_kernel<<<dim3(BS), 1024, 0, stream>>>(ws_maxs, ws_cls, out, ws_top);
    decode_kernel<<<dim3(MAX_DET, BS), 128, 0, stream>>>(
        x0, x1, x2,
        w2[0], b2[0], w2[1], b2[1], w2[2], b2[2],
        w4[0], b4[0], w4[1], b4[1], w4[2], b4[2],
        ws_top, out);
}